// Round 1
// baseline (653.084 us; speedup 1.0000x reference)
//
#include <hip/hip_runtime.h>

#define NN 100000
#define NE 1600000
// IN=128, HID=64, OUT=32

// ---------------- degree count (int atomics) ----------------
__global__ __launch_bounds__(256) void k_deg(const int* __restrict__ dst, int* __restrict__ deg) {
  int i = blockIdx.x * 256 + threadIdx.x;
  if (i < NE) atomicAdd(&deg[dst[i]], 1);
}

// ---------------- dinv = rsqrt(in_deg + 1 self loop) ----------------
__global__ __launch_bounds__(256) void k_dinv(const int* __restrict__ deg, float* __restrict__ dinv) {
  int i = blockIdx.x * 256 + threadIdx.x;
  if (i < NN) dinv[i] = rsqrtf((float)(deg[i] + 1));
}

// ---------------- exclusive prefix sum over deg (single block) ----------------
__global__ __launch_bounds__(1024) void k_scan(const int* __restrict__ deg, int* __restrict__ row_ptr) {
  __shared__ int sums[1024];
  int t = threadIdx.x;
  const int chunk = (NN + 1023) / 1024;  // 98
  int start = t * chunk;
  int end = min(start + chunk, NN);
  int s = 0;
  for (int i = start; i < end; ++i) s += deg[i];
  sums[t] = s;
  __syncthreads();
  // Hillis-Steele inclusive scan
  for (int off = 1; off < 1024; off <<= 1) {
    int v = (t >= off) ? sums[t - off] : 0;
    __syncthreads();
    sums[t] += v;
    __syncthreads();
  }
  int run = (t == 0) ? 0 : sums[t - 1];
  for (int i = start; i < end; ++i) { row_ptr[i] = run; run += deg[i]; }
}

// ---------------- CSR build: bucket edges by dst ----------------
__global__ __launch_bounds__(256) void k_build(const int* __restrict__ src, const int* __restrict__ dst,
                                               const int* __restrict__ row_ptr, int* __restrict__ cnt,
                                               const float* __restrict__ dinv,
                                               int* __restrict__ csr_src, float* __restrict__ csr_w) {
  int e = blockIdx.x * 256 + threadIdx.x;
  if (e >= NE) return;
  int s = src[e], d = dst[e];
  int pos = row_ptr[d] + atomicAdd(&cnt[d], 1);
  csr_src[pos] = s;
  csr_w[pos] = dinv[s] * dinv[d];
}

// ---------------- GEMM1: hpre[N,64] = x[N,128] @ W1[128,64] ----------------
// block = 256 threads -> 64 rows x 64 cols; thread = 4 rows x 4 cols
__global__ __launch_bounds__(256) void k_gemm1(const float* __restrict__ x, const float* __restrict__ W,
                                               float* __restrict__ out) {
  __shared__ float Ws[128 * 64];  // [k][c]  32KB
  __shared__ float Xs[128 * 64];  // [k][r]  32KB (transposed tile)
  int tid = threadIdx.x;
  int row0 = blockIdx.x * 64;
  {
    const float4* Wv = (const float4*)W;
    float4* Wsv = (float4*)Ws;
#pragma unroll
    for (int i = 0; i < 8; ++i) Wsv[tid + 256 * i] = Wv[tid + 256 * i];
  }
  {
#pragma unroll
    for (int i = 0; i < 8; ++i) {
      int idx = tid + 256 * i;  // 0..2047 ; 64 rows * 32 float4
      int r = idx >> 5;         // 0..63
      int k4 = idx & 31;        // 0..31
      float4 v = make_float4(0.f, 0.f, 0.f, 0.f);
      if (row0 + r < NN) v = *(const float4*)(x + (size_t)(row0 + r) * 128 + k4 * 4);
      Xs[(k4 * 4 + 0) * 64 + r] = v.x;
      Xs[(k4 * 4 + 1) * 64 + r] = v.y;
      Xs[(k4 * 4 + 2) * 64 + r] = v.z;
      Xs[(k4 * 4 + 3) * 64 + r] = v.w;
    }
  }
  __syncthreads();
  int cg = tid & 15;   // col group
  int rg = tid >> 4;   // row group
  int c0 = cg * 4, r0 = rg * 4;
  float acc[4][4] = {};
#pragma unroll 8
  for (int k = 0; k < 128; ++k) {
    float4 xv = *(const float4*)&Xs[k * 64 + r0];
    float4 wv = *(const float4*)&Ws[k * 64 + c0];
    float xr[4] = {xv.x, xv.y, xv.z, xv.w};
    float wr[4] = {wv.x, wv.y, wv.z, wv.w};
#pragma unroll
    for (int i = 0; i < 4; ++i)
#pragma unroll
      for (int j = 0; j < 4; ++j) acc[i][j] += xr[i] * wr[j];
  }
#pragma unroll
  for (int i = 0; i < 4; ++i) {
    int row = row0 + r0 + i;
    if (row < NN) {
      float4 o = make_float4(acc[i][0], acc[i][1], acc[i][2], acc[i][3]);
      *(float4*)&out[(size_t)row * 64 + c0] = o;
    }
  }
}

// ---------------- aggregation: out[i] = dinv[i]^2*in[i] + sum_j w_j*in[src_j] (+bias)(relu) ----------
template <bool RELU, bool BIAS>
__global__ __launch_bounds__(256) void k_agg(const float* __restrict__ hin, const int* __restrict__ csr_src,
                                             const float* __restrict__ csr_w, const int* __restrict__ row_ptr,
                                             const int* __restrict__ deg, const float* __restrict__ dinv,
                                             const float* __restrict__ bias, float* __restrict__ out) {
  int gid = blockIdx.x * 256 + threadIdx.x;
  int node = gid >> 6;
  int lane = threadIdx.x & 63;
  if (node >= NN) return;
  float di = dinv[node];
  float acc0 = di * di * hin[(size_t)node * 64 + lane];
  float acc1 = 0.f;
  int start = row_ptr[node];
  int cntv = deg[node];
  int j = 0;
  for (; j + 2 <= cntv; j += 2) {
    int s0 = csr_src[start + j];
    int s1 = csr_src[start + j + 1];
    float w0 = csr_w[start + j];
    float w1 = csr_w[start + j + 1];
    float v0 = hin[(size_t)s0 * 64 + lane];
    float v1 = hin[(size_t)s1 * 64 + lane];
    acc0 += w0 * v0;
    acc1 += w1 * v1;
  }
  if (j < cntv) {
    int s0 = csr_src[start + j];
    acc0 += csr_w[start + j] * hin[(size_t)s0 * 64 + lane];
  }
  float r = acc0 + acc1;
  if (BIAS) r += bias[lane];
  if (RELU) r = fmaxf(r, 0.f);
  out[(size_t)node * 64 + lane] = r;
}

// ---------------- GEMM2: out = [agg2 @ Wmu + bmu | agg2 @ Wls + bls] ----------------
// block = 256 -> 64 rows x 64 cols (cols 0..31 -> mu, 32..63 -> logstd)
__global__ __launch_bounds__(256) void k_gemm2(const float* __restrict__ a, const float* __restrict__ Wmu,
                                               const float* __restrict__ Wls, const float* __restrict__ bmu,
                                               const float* __restrict__ bls, float* __restrict__ out) {
  __shared__ float Ws[64 * 64];  // [k][c]  16KB
  __shared__ float Xs[64 * 64];  // [k][r]  16KB
  int tid = threadIdx.x;
  int row0 = blockIdx.x * 64;
  {
    // Wmu/Wls each 64x32 = 512 float4
    for (int i = tid; i < 512; i += 256) {
      int k = i >> 3, c4 = i & 7;
      ((float4*)Ws)[k * 16 + c4] = ((const float4*)Wmu)[i];
      ((float4*)Ws)[k * 16 + 8 + c4] = ((const float4*)Wls)[i];
    }
  }
  {
#pragma unroll
    for (int i = 0; i < 4; ++i) {
      int idx = tid + 256 * i;  // 0..1023 ; 64 rows * 16 float4
      int r = idx >> 4;         // 0..63
      int k4 = idx & 15;        // 0..15
      float4 v = make_float4(0.f, 0.f, 0.f, 0.f);
      if (row0 + r < NN) v = *(const float4*)(a + (size_t)(row0 + r) * 64 + k4 * 4);
      Xs[(k4 * 4 + 0) * 64 + r] = v.x;
      Xs[(k4 * 4 + 1) * 64 + r] = v.y;
      Xs[(k4 * 4 + 2) * 64 + r] = v.z;
      Xs[(k4 * 4 + 3) * 64 + r] = v.w;
    }
  }
  __syncthreads();
  int cg = tid & 15;
  int rg = tid >> 4;
  int c0 = cg * 4, r0 = rg * 4;
  float acc[4][4] = {};
#pragma unroll 8
  for (int k = 0; k < 64; ++k) {
    float4 xv = *(const float4*)&Xs[k * 64 + r0];
    float4 wv = *(const float4*)&Ws[k * 64 + c0];
    float xr[4] = {xv.x, xv.y, xv.z, xv.w};
    float wr[4] = {wv.x, wv.y, wv.z, wv.w};
#pragma unroll
    for (int i = 0; i < 4; ++i)
#pragma unroll
      for (int j = 0; j < 4; ++j) acc[i][j] += xr[i] * wr[j];
  }
  const float* bsrc = (c0 < 32) ? (bmu + c0) : (bls + (c0 - 32));
  float4 bv = make_float4(bsrc[0], bsrc[1], bsrc[2], bsrc[3]);
#pragma unroll
  for (int i = 0; i < 4; ++i) {
    int row = row0 + r0 + i;
    if (row < NN) {
      float4 o = make_float4(acc[i][0] + bv.x, acc[i][1] + bv.y, acc[i][2] + bv.z, acc[i][3] + bv.w);
      float* dst = (c0 < 32) ? (out + (size_t)row * 32 + c0)
                             : (out + (size_t)NN * 32 + (size_t)row * 32 + (c0 - 32));
      *(float4*)dst = o;
    }
  }
}

extern "C" void kernel_launch(void* const* d_in, const int* in_sizes, int n_in,
                              void* d_out, int out_size, void* d_ws, size_t ws_size,
                              hipStream_t stream) {
  const float* x   = (const float*)d_in[0];
  const int*   ei  = (const int*)d_in[1];
  const float* W1  = (const float*)d_in[2];
  const float* b1  = (const float*)d_in[3];
  const float* Wmu = (const float*)d_in[4];
  const float* bmu = (const float*)d_in[5];
  const float* Wls = (const float*)d_in[6];
  const float* bls = (const float*)d_in[7];
  float* out = (float*)d_out;

  char* ws = (char*)d_ws;
  size_t off = 0;
  auto take = [&](size_t bytes) -> char* {
    char* p = ws + off;
    off = (off + bytes + 255) & ~(size_t)255;
    return p;
  };
  int*   deg     = (int*)take((size_t)NN * 4);
  int*   cnt     = (int*)take((size_t)NN * 4);
  int*   row_ptr = (int*)take((size_t)NN * 4);
  float* dinv    = (float*)take((size_t)NN * 4);
  int*   csr_src = (int*)take((size_t)NE * 4);
  float* csr_w   = (float*)take((size_t)NE * 4);
  float* hpre    = (float*)take((size_t)NN * 64 * 4);  // also reused as agg2
  float* h1      = (float*)take((size_t)NN * 64 * 4);

  const int* srcp = ei;
  const int* dstp = ei + NE;

  hipMemsetAsync(deg, 0, (size_t)NN * 4, stream);
  hipMemsetAsync(cnt, 0, (size_t)NN * 4, stream);
  k_deg<<<(NE + 255) / 256, 256, 0, stream>>>(dstp, deg);
  k_dinv<<<(NN + 255) / 256, 256, 0, stream>>>(deg, dinv);
  k_scan<<<1, 1024, 0, stream>>>(deg, row_ptr);
  k_build<<<(NE + 255) / 256, 256, 0, stream>>>(srcp, dstp, row_ptr, cnt, dinv, csr_src, csr_w);
  k_gemm1<<<(NN + 63) / 64, 256, 0, stream>>>(x, W1, hpre);
  // h1 = relu(A @ hpre + b1)
  k_agg<true, true><<<((size_t)NN * 64 + 255) / 256, 256, 0, stream>>>(hpre, csr_src, csr_w, row_ptr, deg, dinv, b1, h1);
  // agg2 = A @ h1   (reuse hpre buffer)
  k_agg<false, false><<<((size_t)NN * 64 + 255) / 256, 256, 0, stream>>>(h1, csr_src, csr_w, row_ptr, deg, dinv, nullptr, hpre);
  k_gemm2<<<(NN + 63) / 64, 256, 0, stream>>>(hpre, Wmu, Wls, bmu, bls, out);
}

// Round 2
// 503.132 us; speedup vs baseline: 1.2980x; 1.2980x over previous
//
#include <hip/hip_runtime.h>

#define NN 100000
#define NE 1600000
#define NBLK ((NN + 255) / 256)   // 391
// IN=128, HID=64, OUT=32

// ---------------- degree count (int atomics) ----------------
__global__ __launch_bounds__(256) void k_deg(const int* __restrict__ dst, int* __restrict__ deg) {
  int i = blockIdx.x * 256 + threadIdx.x;
  if (i < NE) atomicAdd(&deg[dst[i]], 1);
}

// ---------------- scan level 1: per-256-chunk sums ----------------
__global__ __launch_bounds__(256) void k_blocksum(const int* __restrict__ deg, int* __restrict__ bsum) {
  __shared__ int s[256];
  int t = threadIdx.x;
  int i = blockIdx.x * 256 + t;
  s[t] = (i < NN) ? deg[i] : 0;
  __syncthreads();
  for (int off = 128; off > 0; off >>= 1) {
    if (t < off) s[t] += s[t + off];
    __syncthreads();
  }
  if (t == 0) bsum[blockIdx.x] = s[0];
}

// ---------------- scan level 2: exclusive scan of 391 partials (1 block) ----------------
__global__ __launch_bounds__(512) void k_scanb(const int* __restrict__ bsum, int* __restrict__ boff) {
  __shared__ int s[512];
  int t = threadIdx.x;
  int v = (t < NBLK) ? bsum[t] : 0;
  s[t] = v;
  __syncthreads();
  for (int off = 1; off < 512; off <<= 1) {
    int u = (t >= off) ? s[t - off] : 0;
    __syncthreads();
    s[t] += u;
    __syncthreads();
  }
  if (t < NBLK) boff[t] = s[t] - v;  // exclusive
}

// ---------------- scan level 3: in-block exclusive scan + offset -> row_ptr ; also dinv ----------------
__global__ __launch_bounds__(256) void k_rowptr(const int* __restrict__ deg, const int* __restrict__ boff,
                                                int* __restrict__ row_ptr, float* __restrict__ dinv) {
  __shared__ int s[256];
  int t = threadIdx.x;
  int i = blockIdx.x * 256 + t;
  int v = (i < NN) ? deg[i] : 0;
  s[t] = v;
  __syncthreads();
  for (int off = 1; off < 256; off <<= 1) {
    int u = (t >= off) ? s[t - off] : 0;
    __syncthreads();
    s[t] += u;
    __syncthreads();
  }
  if (i < NN) {
    row_ptr[i] = boff[blockIdx.x] + s[t] - v;
    dinv[i] = rsqrtf((float)(v + 1));
  }
}

// ---------------- CSR build: bucket edges by dst ----------------
__global__ __launch_bounds__(256) void k_build(const int* __restrict__ src, const int* __restrict__ dst,
                                               const int* __restrict__ row_ptr, int* __restrict__ cnt,
                                               const float* __restrict__ dinv,
                                               int* __restrict__ csr_src, float* __restrict__ csr_w) {
  int e = blockIdx.x * 256 + threadIdx.x;
  if (e >= NE) return;
  int s = src[e], d = dst[e];
  int pos = row_ptr[d] + atomicAdd(&cnt[d], 1);
  csr_src[pos] = s;
  csr_w[pos] = dinv[s] * dinv[d];
}

// ---------------- GEMM1: hpre[N,64] = x[N,128] @ W1[128,64] ----------------
__global__ __launch_bounds__(256) void k_gemm1(const float* __restrict__ x, const float* __restrict__ W,
                                               float* __restrict__ out) {
  __shared__ float Ws[128 * 64];  // [k][c]  32KB
  __shared__ float Xs[128 * 64];  // [k][r]  32KB (transposed tile)
  int tid = threadIdx.x;
  int row0 = blockIdx.x * 64;
  {
    const float4* Wv = (const float4*)W;
    float4* Wsv = (float4*)Ws;
#pragma unroll
    for (int i = 0; i < 8; ++i) Wsv[tid + 256 * i] = Wv[tid + 256 * i];
  }
  {
#pragma unroll
    for (int i = 0; i < 8; ++i) {
      int idx = tid + 256 * i;  // 0..2047 ; 64 rows * 32 float4
      int r = idx >> 5;         // 0..63
      int k4 = idx & 31;        // 0..31
      float4 v = make_float4(0.f, 0.f, 0.f, 0.f);
      if (row0 + r < NN) v = *(const float4*)(x + (size_t)(row0 + r) * 128 + k4 * 4);
      Xs[(k4 * 4 + 0) * 64 + r] = v.x;
      Xs[(k4 * 4 + 1) * 64 + r] = v.y;
      Xs[(k4 * 4 + 2) * 64 + r] = v.z;
      Xs[(k4 * 4 + 3) * 64 + r] = v.w;
    }
  }
  __syncthreads();
  int cg = tid & 15;   // col group
  int rg = tid >> 4;   // row group
  int c0 = cg * 4, r0 = rg * 4;
  float acc[4][4] = {};
#pragma unroll 8
  for (int k = 0; k < 128; ++k) {
    float4 xv = *(const float4*)&Xs[k * 64 + r0];
    float4 wv = *(const float4*)&Ws[k * 64 + c0];
    float xr[4] = {xv.x, xv.y, xv.z, xv.w};
    float wr[4] = {wv.x, wv.y, wv.z, wv.w};
#pragma unroll
    for (int i = 0; i < 4; ++i)
#pragma unroll
      for (int j = 0; j < 4; ++j) acc[i][j] += xr[i] * wr[j];
  }
#pragma unroll
  for (int i = 0; i < 4; ++i) {
    int row = row0 + r0 + i;
    if (row < NN) {
      float4 o = make_float4(acc[i][0], acc[i][1], acc[i][2], acc[i][3]);
      *(float4*)&out[(size_t)row * 64 + c0] = o;
    }
  }
}

// ---------------- aggregation: out[i] = dinv[i]^2*in[i] + sum_j w_j*in[src_j] (+bias)(relu) ----------
template <bool RELU, bool BIAS>
__global__ __launch_bounds__(256) void k_agg(const float* __restrict__ hin, const int* __restrict__ csr_src,
                                             const float* __restrict__ csr_w, const int* __restrict__ row_ptr,
                                             const int* __restrict__ deg, const float* __restrict__ dinv,
                                             const float* __restrict__ bias, float* __restrict__ out) {
  int gid = blockIdx.x * 256 + threadIdx.x;
  int node = gid >> 6;
  int lane = threadIdx.x & 63;
  if (node >= NN) return;
  float di = dinv[node];
  float acc0 = di * di * hin[(size_t)node * 64 + lane];
  float acc1 = 0.f;
  int start = row_ptr[node];
  int cntv = deg[node];
  int j = 0;
  for (; j + 2 <= cntv; j += 2) {
    int s0 = csr_src[start + j];
    int s1 = csr_src[start + j + 1];
    float w0 = csr_w[start + j];
    float w1 = csr_w[start + j + 1];
    float v0 = hin[(size_t)s0 * 64 + lane];
    float v1 = hin[(size_t)s1 * 64 + lane];
    acc0 += w0 * v0;
    acc1 += w1 * v1;
  }
  if (j < cntv) {
    int s0 = csr_src[start + j];
    acc0 += csr_w[start + j] * hin[(size_t)s0 * 64 + lane];
  }
  float r = acc0 + acc1;
  if (BIAS) r += bias[lane];
  if (RELU) r = fmaxf(r, 0.f);
  out[(size_t)node * 64 + lane] = r;
}

// ---------------- GEMM2: out = [agg2 @ Wmu + bmu | agg2 @ Wls + bls] ----------------
__global__ __launch_bounds__(256) void k_gemm2(const float* __restrict__ a, const float* __restrict__ Wmu,
                                               const float* __restrict__ Wls, const float* __restrict__ bmu,
                                               const float* __restrict__ bls, float* __restrict__ out) {
  __shared__ float Ws[64 * 64];  // [k][c]  16KB
  __shared__ float Xs[64 * 64];  // [k][r]  16KB
  int tid = threadIdx.x;
  int row0 = blockIdx.x * 64;
  {
    for (int i = tid; i < 512; i += 256) {
      int k = i >> 3, c4 = i & 7;
      ((float4*)Ws)[k * 16 + c4] = ((const float4*)Wmu)[i];
      ((float4*)Ws)[k * 16 + 8 + c4] = ((const float4*)Wls)[i];
    }
  }
  {
#pragma unroll
    for (int i = 0; i < 4; ++i) {
      int idx = tid + 256 * i;  // 0..1023 ; 64 rows * 16 float4
      int r = idx >> 4;         // 0..63
      int k4 = idx & 15;        // 0..15
      float4 v = make_float4(0.f, 0.f, 0.f, 0.f);
      if (row0 + r < NN) v = *(const float4*)(a + (size_t)(row0 + r) * 64 + k4 * 4);
      Xs[(k4 * 4 + 0) * 64 + r] = v.x;
      Xs[(k4 * 4 + 1) * 64 + r] = v.y;
      Xs[(k4 * 4 + 2) * 64 + r] = v.z;
      Xs[(k4 * 4 + 3) * 64 + r] = v.w;
    }
  }
  __syncthreads();
  int cg = tid & 15;
  int rg = tid >> 4;
  int c0 = cg * 4, r0 = rg * 4;
  float acc[4][4] = {};
#pragma unroll 8
  for (int k = 0; k < 64; ++k) {
    float4 xv = *(const float4*)&Xs[k * 64 + r0];
    float4 wv = *(const float4*)&Ws[k * 64 + c0];
    float xr[4] = {xv.x, xv.y, xv.z, xv.w};
    float wr[4] = {wv.x, wv.y, wv.z, wv.w};
#pragma unroll
    for (int i = 0; i < 4; ++i)
#pragma unroll
      for (int j = 0; j < 4; ++j) acc[i][j] += xr[i] * wr[j];
  }
  const float* bsrc = (c0 < 32) ? (bmu + c0) : (bls + (c0 - 32));
  float4 bv = make_float4(bsrc[0], bsrc[1], bsrc[2], bsrc[3]);
#pragma unroll
  for (int i = 0; i < 4; ++i) {
    int row = row0 + r0 + i;
    if (row < NN) {
      float4 o = make_float4(acc[i][0] + bv.x, acc[i][1] + bv.y, acc[i][2] + bv.z, acc[i][3] + bv.w);
      float* dst = (c0 < 32) ? (out + (size_t)row * 32 + c0)
                             : (out + (size_t)NN * 32 + (size_t)row * 32 + (c0 - 32));
      *(float4*)dst = o;
    }
  }
}

extern "C" void kernel_launch(void* const* d_in, const int* in_sizes, int n_in,
                              void* d_out, int out_size, void* d_ws, size_t ws_size,
                              hipStream_t stream) {
  const float* x   = (const float*)d_in[0];
  const int*   ei  = (const int*)d_in[1];
  const float* W1  = (const float*)d_in[2];
  const float* b1  = (const float*)d_in[3];
  const float* Wmu = (const float*)d_in[4];
  const float* bmu = (const float*)d_in[5];
  const float* Wls = (const float*)d_in[6];
  const float* bls = (const float*)d_in[7];
  float* out = (float*)d_out;

  char* ws = (char*)d_ws;
  size_t off = 0;
  auto take = [&](size_t bytes) -> char* {
    char* p = ws + off;
    off = (off + bytes + 255) & ~(size_t)255;
    return p;
  };
  int*   deg     = (int*)take((size_t)NN * 4);
  int*   cnt     = (int*)take((size_t)NN * 4);
  int*   row_ptr = (int*)take((size_t)NN * 4);
  float* dinv    = (float*)take((size_t)NN * 4);
  int*   bsum    = (int*)take((size_t)NBLK * 4);
  int*   boff    = (int*)take((size_t)NBLK * 4);
  int*   csr_src = (int*)take((size_t)NE * 4);
  float* csr_w   = (float*)take((size_t)NE * 4);
  float* hpre    = (float*)take((size_t)NN * 64 * 4);  // also reused as agg2
  float* h1      = (float*)take((size_t)NN * 64 * 4);

  const int* srcp = ei;
  const int* dstp = ei + NE;

  hipMemsetAsync(deg, 0, (size_t)NN * 4, stream);
  hipMemsetAsync(cnt, 0, (size_t)NN * 4, stream);
  k_deg<<<(NE + 255) / 256, 256, 0, stream>>>(dstp, deg);
  k_blocksum<<<NBLK, 256, 0, stream>>>(deg, bsum);
  k_scanb<<<1, 512, 0, stream>>>(bsum, boff);
  k_rowptr<<<NBLK, 256, 0, stream>>>(deg, boff, row_ptr, dinv);
  k_build<<<(NE + 255) / 256, 256, 0, stream>>>(srcp, dstp, row_ptr, cnt, dinv, csr_src, csr_w);
  k_gemm1<<<(NN + 63) / 64, 256, 0, stream>>>(x, W1, hpre);
  // h1 = relu(A @ hpre + b1)
  k_agg<true, true><<<((size_t)NN * 64 + 255) / 256, 256, 0, stream>>>(hpre, csr_src, csr_w, row_ptr, deg, dinv, b1, h1);
  // agg2 = A @ h1   (reuse hpre buffer)
  k_agg<false, false><<<((size_t)NN * 64 + 255) / 256, 256, 0, stream>>>(h1, csr_src, csr_w, row_ptr, deg, dinv, nullptr, hpre);
  k_gemm2<<<(NN + 63) / 64, 256, 0, stream>>>(hpre, Wmu, Wls, bmu, bls, out);
}

// Round 3
// 450.453 us; speedup vs baseline: 1.4498x; 1.1169x over previous
//
#include <hip/hip_runtime.h>

#define NN 100000
#define NE 1600000
#define NBLK ((NN + 255) / 256)   // 391
// IN=128, HID=64, OUT=32

// ---------------- degree count (int atomics) ----------------
__global__ __launch_bounds__(256) void k_deg(const int* __restrict__ dst, int* __restrict__ deg) {
  int i = blockIdx.x * 256 + threadIdx.x;
  if (i < NE) atomicAdd(&deg[dst[i]], 1);
}

// ---------------- scan level 1: per-256-chunk sums ----------------
__global__ __launch_bounds__(256) void k_blocksum(const int* __restrict__ deg, int* __restrict__ bsum) {
  __shared__ int s[256];
  int t = threadIdx.x;
  int i = blockIdx.x * 256 + t;
  s[t] = (i < NN) ? deg[i] : 0;
  __syncthreads();
  for (int off = 128; off > 0; off >>= 1) {
    if (t < off) s[t] += s[t + off];
    __syncthreads();
  }
  if (t == 0) bsum[blockIdx.x] = s[0];
}

// ---------------- scan level 2: exclusive scan of 391 partials (1 block) ----------------
__global__ __launch_bounds__(512) void k_scanb(const int* __restrict__ bsum, int* __restrict__ boff) {
  __shared__ int s[512];
  int t = threadIdx.x;
  int v = (t < NBLK) ? bsum[t] : 0;
  s[t] = v;
  __syncthreads();
  for (int off = 1; off < 512; off <<= 1) {
    int u = (t >= off) ? s[t - off] : 0;
    __syncthreads();
    s[t] += u;
    __syncthreads();
  }
  if (t < NBLK) boff[t] = s[t] - v;  // exclusive
}

// ---------------- scan level 3: in-block exclusive scan + offset -> row_ptr ; also dinv ----------------
__global__ __launch_bounds__(256) void k_rowptr(const int* __restrict__ deg, const int* __restrict__ boff,
                                                int* __restrict__ row_ptr, float* __restrict__ dinv) {
  __shared__ int s[256];
  int t = threadIdx.x;
  int i = blockIdx.x * 256 + t;
  int v = (i < NN) ? deg[i] : 0;
  s[t] = v;
  __syncthreads();
  for (int off = 1; off < 256; off <<= 1) {
    int u = (t >= off) ? s[t - off] : 0;
    __syncthreads();
    s[t] += u;
    __syncthreads();
  }
  if (i < NN) {
    row_ptr[i] = boff[blockIdx.x] + s[t] - v;
    dinv[i] = rsqrtf((float)(v + 1));
  }
}

// ---------------- CSR build: bucket edges by dst, packed {src, w} ----------------
__global__ __launch_bounds__(256) void k_build(const int* __restrict__ src, const int* __restrict__ dst,
                                               const int* __restrict__ row_ptr, int* __restrict__ cnt,
                                               const float* __restrict__ dinv,
                                               int2* __restrict__ csr) {
  int e = blockIdx.x * 256 + threadIdx.x;
  if (e >= NE) return;
  int s = src[e], d = dst[e];
  int pos = row_ptr[d] + atomicAdd(&cnt[d], 1);
  float w = dinv[s] * dinv[d];
  csr[pos] = make_int2(s, __float_as_int(w));
}

// ---------------- GEMM1: hpre[N,64] = x[N,128] @ W1[128,64] ----------------
__global__ __launch_bounds__(256) void k_gemm1(const float* __restrict__ x, const float* __restrict__ W,
                                               float* __restrict__ out) {
  __shared__ float Ws[128 * 64];  // [k][c]  32KB
  __shared__ float Xs[128 * 64];  // [k][r]  32KB (transposed tile)
  int tid = threadIdx.x;
  int row0 = blockIdx.x * 64;
  {
    const float4* Wv = (const float4*)W;
    float4* Wsv = (float4*)Ws;
#pragma unroll
    for (int i = 0; i < 8; ++i) Wsv[tid + 256 * i] = Wv[tid + 256 * i];
  }
  {
#pragma unroll
    for (int i = 0; i < 8; ++i) {
      int idx = tid + 256 * i;  // 0..2047 ; 64 rows * 32 float4
      int r = idx >> 5;         // 0..63
      int k4 = idx & 31;        // 0..31
      float4 v = make_float4(0.f, 0.f, 0.f, 0.f);
      if (row0 + r < NN) v = *(const float4*)(x + (size_t)(row0 + r) * 128 + k4 * 4);
      Xs[(k4 * 4 + 0) * 64 + r] = v.x;
      Xs[(k4 * 4 + 1) * 64 + r] = v.y;
      Xs[(k4 * 4 + 2) * 64 + r] = v.z;
      Xs[(k4 * 4 + 3) * 64 + r] = v.w;
    }
  }
  __syncthreads();
  int cg = tid & 15;   // col group
  int rg = tid >> 4;   // row group
  int c0 = cg * 4, r0 = rg * 4;
  float acc[4][4] = {};
#pragma unroll 8
  for (int k = 0; k < 128; ++k) {
    float4 xv = *(const float4*)&Xs[k * 64 + r0];
    float4 wv = *(const float4*)&Ws[k * 64 + c0];
    float xr[4] = {xv.x, xv.y, xv.z, xv.w};
    float wr[4] = {wv.x, wv.y, wv.z, wv.w};
#pragma unroll
    for (int i = 0; i < 4; ++i)
#pragma unroll
      for (int j = 0; j < 4; ++j) acc[i][j] += xr[i] * wr[j];
  }
#pragma unroll
  for (int i = 0; i < 4; ++i) {
    int row = row0 + r0 + i;
    if (row < NN) {
      float4 o = make_float4(acc[i][0], acc[i][1], acc[i][2], acc[i][3]);
      *(float4*)&out[(size_t)row * 64 + c0] = o;
    }
  }
}

// ---------------- aggregation: out[i] = dinv[i]^2*in[i] + sum_j w_j*in[src_j] (+bias)(relu) ----------
// wave per node, lane = channel; unroll-4 for memory-level parallelism
template <bool RELU, bool BIAS>
__global__ __launch_bounds__(256) void k_agg(const float* __restrict__ hin, const int2* __restrict__ csr,
                                             const int* __restrict__ row_ptr, const int* __restrict__ deg,
                                             const float* __restrict__ dinv, const float* __restrict__ bias,
                                             float* __restrict__ out) {
  int gid = blockIdx.x * 256 + threadIdx.x;
  int node = gid >> 6;
  int lane = threadIdx.x & 63;
  if (node >= NN) return;
  float di = dinv[node];
  float acc0 = di * di * hin[(size_t)node * 64 + lane];
  float acc1 = 0.f, acc2 = 0.f, acc3 = 0.f;
  int start = row_ptr[node];
  int n = deg[node];
  int j = 0;
  for (; j + 4 <= n; j += 4) {
    int2 e0 = csr[start + j];
    int2 e1 = csr[start + j + 1];
    int2 e2 = csr[start + j + 2];
    int2 e3 = csr[start + j + 3];
    float v0 = hin[(size_t)e0.x * 64 + lane];
    float v1 = hin[(size_t)e1.x * 64 + lane];
    float v2 = hin[(size_t)e2.x * 64 + lane];
    float v3 = hin[(size_t)e3.x * 64 + lane];
    acc0 += __int_as_float(e0.y) * v0;
    acc1 += __int_as_float(e1.y) * v1;
    acc2 += __int_as_float(e2.y) * v2;
    acc3 += __int_as_float(e3.y) * v3;
  }
  for (; j < n; ++j) {
    int2 e = csr[start + j];
    acc0 += __int_as_float(e.y) * hin[(size_t)e.x * 64 + lane];
  }
  float r = (acc0 + acc1) + (acc2 + acc3);
  if (BIAS) r += bias[lane];
  if (RELU) r = fmaxf(r, 0.f);
  out[(size_t)node * 64 + lane] = r;
}

// ---------------- GEMM2: out = [agg2 @ Wmu + bmu | agg2 @ Wls + bls] ----------------
__global__ __launch_bounds__(256) void k_gemm2(const float* __restrict__ a, const float* __restrict__ Wmu,
                                               const float* __restrict__ Wls, const float* __restrict__ bmu,
                                               const float* __restrict__ bls, float* __restrict__ out) {
  __shared__ float Ws[64 * 64];  // [k][c]  16KB
  __shared__ float Xs[64 * 64];  // [k][r]  16KB
  int tid = threadIdx.x;
  int row0 = blockIdx.x * 64;
  {
    for (int i = tid; i < 512; i += 256) {
      int k = i >> 3, c4 = i & 7;
      ((float4*)Ws)[k * 16 + c4] = ((const float4*)Wmu)[i];
      ((float4*)Ws)[k * 16 + 8 + c4] = ((const float4*)Wls)[i];
    }
  }
  {
#pragma unroll
    for (int i = 0; i < 4; ++i) {
      int idx = tid + 256 * i;  // 0..1023 ; 64 rows * 16 float4
      int r = idx >> 4;         // 0..63
      int k4 = idx & 15;        // 0..15
      float4 v = make_float4(0.f, 0.f, 0.f, 0.f);
      if (row0 + r < NN) v = *(const float4*)(a + (size_t)(row0 + r) * 64 + k4 * 4);
      Xs[(k4 * 4 + 0) * 64 + r] = v.x;
      Xs[(k4 * 4 + 1) * 64 + r] = v.y;
      Xs[(k4 * 4 + 2) * 64 + r] = v.z;
      Xs[(k4 * 4 + 3) * 64 + r] = v.w;
    }
  }
  __syncthreads();
  int cg = tid & 15;
  int rg = tid >> 4;
  int c0 = cg * 4, r0 = rg * 4;
  float acc[4][4] = {};
#pragma unroll 8
  for (int k = 0; k < 64; ++k) {
    float4 xv = *(const float4*)&Xs[k * 64 + r0];
    float4 wv = *(const float4*)&Ws[k * 64 + c0];
    float xr[4] = {xv.x, xv.y, xv.z, xv.w};
    float wr[4] = {wv.x, wv.y, wv.z, wv.w};
#pragma unroll
    for (int i = 0; i < 4; ++i)
#pragma unroll
      for (int j = 0; j < 4; ++j) acc[i][j] += xr[i] * wr[j];
  }
  const float* bsrc = (c0 < 32) ? (bmu + c0) : (bls + (c0 - 32));
  float4 bv = make_float4(bsrc[0], bsrc[1], bsrc[2], bsrc[3]);
#pragma unroll
  for (int i = 0; i < 4; ++i) {
    int row = row0 + r0 + i;
    if (row < NN) {
      float4 o = make_float4(acc[i][0] + bv.x, acc[i][1] + bv.y, acc[i][2] + bv.z, acc[i][3] + bv.w);
      float* dst = (c0 < 32) ? (out + (size_t)row * 32 + c0)
                             : (out + (size_t)NN * 32 + (size_t)row * 32 + (c0 - 32));
      *(float4*)dst = o;
    }
  }
}

extern "C" void kernel_launch(void* const* d_in, const int* in_sizes, int n_in,
                              void* d_out, int out_size, void* d_ws, size_t ws_size,
                              hipStream_t stream) {
  const float* x   = (const float*)d_in[0];
  const int*   ei  = (const int*)d_in[1];
  const float* W1  = (const float*)d_in[2];
  const float* b1  = (const float*)d_in[3];
  const float* Wmu = (const float*)d_in[4];
  const float* bmu = (const float*)d_in[5];
  const float* Wls = (const float*)d_in[6];
  const float* bls = (const float*)d_in[7];
  float* out = (float*)d_out;

  char* ws = (char*)d_ws;
  size_t off = 0;
  auto take = [&](size_t bytes) -> char* {
    char* p = ws + off;
    off = (off + bytes + 255) & ~(size_t)255;
    return p;
  };
  int*   deg     = (int*)take((size_t)NN * 4);
  int*   cnt     = (int*)take((size_t)NN * 4);
  int*   row_ptr = (int*)take((size_t)NN * 4);
  float* dinv    = (float*)take((size_t)NN * 4);
  int*   bsum    = (int*)take((size_t)NBLK * 4);
  int*   boff    = (int*)take((size_t)NBLK * 4);
  int2*  csr     = (int2*)take((size_t)NE * 8);
  float* hpre    = (float*)take((size_t)NN * 64 * 4);  // also reused as agg2
  float* h1      = (float*)take((size_t)NN * 64 * 4);

  const int* srcp = ei;
  const int* dstp = ei + NE;

  hipMemsetAsync(deg, 0, (size_t)NN * 4, stream);
  hipMemsetAsync(cnt, 0, (size_t)NN * 4, stream);
  k_deg<<<(NE + 255) / 256, 256, 0, stream>>>(dstp, deg);
  k_blocksum<<<NBLK, 256, 0, stream>>>(deg, bsum);
  k_scanb<<<1, 512, 0, stream>>>(bsum, boff);
  k_rowptr<<<NBLK, 256, 0, stream>>>(deg, boff, row_ptr, dinv);
  k_build<<<(NE + 255) / 256, 256, 0, stream>>>(srcp, dstp, row_ptr, cnt, dinv, csr);
  k_gemm1<<<(NN + 63) / 64, 256, 0, stream>>>(x, W1, hpre);
  // h1 = relu(A @ hpre + b1)
  k_agg<true, true><<<((size_t)NN * 64 + 255) / 256, 256, 0, stream>>>(hpre, csr, row_ptr, deg, dinv, b1, h1);
  // agg2 = A @ h1   (reuse hpre buffer)
  k_agg<false, false><<<((size_t)NN * 64 + 255) / 256, 256, 0, stream>>>(h1, csr, row_ptr, deg, dinv, nullptr, hpre);
  k_gemm2<<<(NN + 63) / 64, 256, 0, stream>>>(hpre, Wmu, Wls, bmu, bls, out);
}